// Round 4
// baseline (22488.570 us; speedup 1.0000x reference)
//
#include <hip/hip_runtime.h>
#include <stdint.h>

#define BATCH 256
#define SEQ   365
#define HID   256
#define INSZ  32
#define NGATE (4*HID)        // 1024 gate columns
#define KTOT  (INSZ+HID)     // 288 combined K
#define AS    296            // padded K stride in shorts (592B rows, 16B aligned)
#define NBLK  512            // 8 groups x 2 row-halves x 32 col-slices
#define TBR   16             // batch rows per block
#define NCOLS 32             // gate cols per block (8 hidden x {f,i,o,g})
#define GS    33             // gate_lds row stride (floats)
#define GPL   (16*GS)        // gate_lds plane stride

typedef __bf16 bf16x8 __attribute__((ext_vector_type(8)));
typedef short  s16x8  __attribute__((ext_vector_type(8)));
typedef float  f32x4  __attribute__((ext_vector_type(4)));

__device__ __forceinline__ unsigned short f2bf(float f) {
    unsigned u = __float_as_uint(f);
    u += 0x7FFFu + ((u >> 16) & 1u);          // round-to-nearest-even
    return (unsigned short)(u >> 16);
}
__device__ __forceinline__ float bf2f(unsigned short h) {
    return __uint_as_float(((unsigned)h) << 16);
}
__device__ __forceinline__ float sigm(float x) { return 1.f / (1.f + __expf(-x)); }
__device__ __forceinline__ float tanh_f(float x) {
    float e = __expf(-2.f * fabsf(x));
    float r = (1.f - e) / (1.f + e);
    return copysignf(r, x);
}

__global__ void __launch_bounds__(256, 2) lstm_kernel(
    const float* __restrict__ x,     // [B][SEQ][INSZ]
    const float* __restrict__ w_ih,  // [INSZ][NGATE]
    const float* __restrict__ w_hh,  // [HID][NGATE]
    const float* __restrict__ bias,  // [NGATE]
    const float* __restrict__ fc_w,  // [HID]
    const float* __restrict__ fc_b,  // [1]
    float* __restrict__ out,         // [B]
    float* __restrict__ h_n,         // [B][SEQ][HID]
    float* __restrict__ c_n,         // [B][SEQ][HID]
    unsigned* __restrict__ h_ex,     // ws: [2][B][HID] fp32 bits
    int* __restrict__ flags)         // ws: [NBLK]
{
    __shared__ short w_hi[NCOLS*AS];     // W^T hi  [local_col][k]
    __shared__ short w_lo[NCOLS*AS];     // W^T lo
    __shared__ short a_hi[TBR*AS];       // A=[x|h] hi  [row][k]
    __shared__ short a_lo[TBR*AS];       // A=[x|h] lo
    __shared__ float gate_lds[2*GPL];    // two K-half planes [kh][16][GS]

    const int tid = threadIdx.x;
    const int bid = blockIdx.x;
    const int cs  = bid >> 4;            // col-slice 0..31 (owns hidden cs*8..+8)
    const int grp = bid & 15;            // sync group 0..15
    const int g   = grp >> 1;            // batch group 0..7
    const int rh  = grp & 1;             // row half
    const int b0  = g*32 + rh*16;        // first batch row of this block

    // ---- one-time: stage W^T (w_ih stacked over w_hh) as bf16 hi/lo pairs ----
    for (int idx = tid; idx < NCOLS*KTOT; idx += 256) {
        int lc = idx / KTOT;             // local col: chunk*8+u, chunk 0=f,1=i,2=o,3=g
        int k  = idx - lc*KTOT;
        int chunk = lc >> 3, u = lc & 7;
        int n = chunk*HID + cs*8 + u;    // global gate column
        float v = (k < INSZ) ? w_ih[k*NGATE + n] : w_hh[(k-INSZ)*NGATE + n];
        unsigned short hi = f2bf(v);
        unsigned short lo = f2bf(v - bf2f(hi));
        w_hi[lc*AS + k] = (short)hi;
        w_lo[lc*AS + k] = (short)lo;
    }

    // ---- epilogue ownership: tid<128 -> (row r, hidden sub u) ----
    const int er = tid >> 3;             // 0..31 (valid rows: <16)
    const int eu = tid & 7;
    const int jg = cs*8 + eu;            // global hidden index
    const float bf_ = bias[jg];
    const float bi_ = bias[HID   + jg];
    const float bo_ = bias[2*HID + jg];
    const float bg_ = bias[3*HID + jg];
    float c_reg = 0.f;

    // ---- MFMA fragment addressing: 4 waves = 2 N-tiles x 2 K-halves ----
    const int lane = tid & 63, wv = tid >> 6;
    const int nt = wv & 1, kh = wv >> 1;
    const int l15 = lane & 15, kq = lane >> 4;
    const short* aph = &a_hi[l15*AS + kq*8];
    const short* apl = &a_lo[l15*AS + kq*8];
    const short* bph = &w_hi[(nt*16 + l15)*AS + kq*8];
    const short* bpl = &w_lo[(nt*16 + l15)*AS + kq*8];
    const int kbeg = kh*5, kend = kbeg + 5 - kh;   // kh=0: 0..4, kh=1: 5..8

    for (int s = 0; s < SEQ; ++s) {
        const int pw = s & 1, pr = pw ^ 1;

        // ---- wait for the 32 blocks of this sync group to publish step s-1 ----
        if (s > 0 && tid < 32) {
            const int peer = tid*16 + grp;
            while (__hip_atomic_load(&flags[peer], __ATOMIC_ACQUIRE,
                                     __HIP_MEMORY_SCOPE_AGENT) < s)
                __builtin_amdgcn_s_sleep(1);
        }
        __syncthreads();

        // ---- stage A: x part (fp32 -> hi/lo bf16) ----
        for (int i = tid; i < TBR*INSZ; i += 256) {
            int r = i >> 5, k = i & 31;
            float v = x[((size_t)(b0+r)*SEQ + s)*INSZ + k];
            unsigned short hi = f2bf(v);
            a_hi[r*AS + k] = (short)hi;
            a_lo[r*AS + k] = (short)f2bf(v - bf2f(hi));
        }
        // ---- stage A: h part (fp32 exchange -> hi/lo bf16) ----
        if (s > 0) {
            const unsigned* src = h_ex + (size_t)pr*BATCH*HID;
            for (int i = tid; i < TBR*HID; i += 256) {   // 16 iters
                int r = i >> 8, j = i & 255;
                unsigned u = __hip_atomic_load(&src[(size_t)(b0+r)*HID + j],
                                               __ATOMIC_RELAXED, __HIP_MEMORY_SCOPE_AGENT);
                float v = __uint_as_float(u);
                unsigned short hi = f2bf(v);
                a_hi[r*AS + INSZ + j] = (short)hi;
                a_lo[r*AS + INSZ + j] = (short)f2bf(v - bf2f(hi));
            }
        } else {
            for (int i = tid; i < TBR*HID; i += 256) {
                int r = i >> 8, j = i & 255;
                a_hi[r*AS + INSZ + j] = 0;
                a_lo[r*AS + INSZ + j] = 0;
            }
        }
        __syncthreads();

        // ---- gates: A[16x288] @ W-slice via hi/lo MFMAs (Al*Wl dropped) ----
        {
            f32x4 a0 = {0.f,0.f,0.f,0.f}, a1 = a0, a2 = a0;
            for (int kk = kbeg; kk < kend; ++kk) {
                bf16x8 ah = __builtin_bit_cast(bf16x8, *(const s16x8*)(aph + kk*32));
                bf16x8 al = __builtin_bit_cast(bf16x8, *(const s16x8*)(apl + kk*32));
                bf16x8 bh = __builtin_bit_cast(bf16x8, *(const s16x8*)(bph + kk*32));
                bf16x8 bl = __builtin_bit_cast(bf16x8, *(const s16x8*)(bpl + kk*32));
                a0 = __builtin_amdgcn_mfma_f32_16x16x32_bf16(ah, bh, a0, 0, 0, 0);
                a1 = __builtin_amdgcn_mfma_f32_16x16x32_bf16(ah, bl, a1, 0, 0, 0);
                a2 = __builtin_amdgcn_mfma_f32_16x16x32_bf16(al, bh, a2, 0, 0, 0);
            }
            f32x4 gv = a0 + a1 + a2;
            // D layout: col = lane&15, row = (lane>>4)*4 + i  [m89-verified]
            int col = nt*16 + l15, rb = kq*4;
            #pragma unroll
            for (int i = 0; i < 4; ++i)
                gate_lds[kh*GPL + (rb+i)*GS + col] = gv[i];
        }
        __syncthreads();

        // ---- epilogue: sum K-halves, combine f,i,o,g; publish h; write outputs ----
        if (tid < 128) {
            const float* g0 = &gate_lds[er*GS];
            const float* g1 = &gate_lds[GPL + er*GS];
            float f  = g0[eu]      + g1[eu]      + bf_;
            float ii = g0[8 + eu]  + g1[8 + eu]  + bi_;
            float o  = g0[16 + eu] + g1[16 + eu] + bo_;
            float gg = g0[24 + eu] + g1[24 + eu] + bg_;
            float cn = sigm(f)*c_reg + sigm(ii)*tanh_f(gg);
            float hn = sigm(o)*tanh_f(cn);
            c_reg = cn;
            size_t oi = ((size_t)(b0+er)*SEQ + s)*HID + jg;
            h_n[oi] = hn;
            c_n[oi] = cn;
            __hip_atomic_store(&h_ex[(size_t)pw*BATCH*HID + (size_t)(b0+er)*HID + jg],
                               __float_as_uint(hn),
                               __ATOMIC_RELAXED, __HIP_MEMORY_SCOPE_AGENT);
        }
        __threadfence();
        __syncthreads();
        if (tid == 0)
            __hip_atomic_store(&flags[bid], s+1, __ATOMIC_RELEASE,
                               __HIP_MEMORY_SCOPE_AGENT);
    }

    // ---- final FC: cs==0 blocks compute out[b] for their 16 rows ----
    if (cs == 0) {
        if (tid < 32) {
            while (__hip_atomic_load(&flags[tid*16 + grp], __ATOMIC_ACQUIRE,
                                     __HIP_MEMORY_SCOPE_AGENT) < SEQ)
                __builtin_amdgcn_s_sleep(1);
        }
        __syncthreads();
        const unsigned* hl = h_ex + (size_t)((SEQ-1) & 1)*BATCH*HID;
        {
            int r = tid >> 4, seg = tid & 15;
            float acc = 0.f;
            #pragma unroll
            for (int d = 0; d < 16; ++d) {
                unsigned u = __hip_atomic_load(&hl[(size_t)(b0+r)*HID + seg*16 + d],
                                               __ATOMIC_RELAXED, __HIP_MEMORY_SCOPE_AGENT);
                acc += __uint_as_float(u) * fc_w[seg*16 + d];
            }
            gate_lds[r*16 + seg] = acc;
        }
        __syncthreads();
        if (tid < TBR) {
            float acc = fc_b[0];
            #pragma unroll
            for (int q = 0; q < 16; ++q) acc += gate_lds[tid*16 + q];
            out[b0 + tid] = acc;
        }
    }
}

extern "C" void kernel_launch(void* const* d_in, const int* in_sizes, int n_in,
                              void* d_out, int out_size, void* d_ws, size_t ws_size,
                              hipStream_t stream) {
    const float* x    = (const float*)d_in[0];
    const float* w_ih = (const float*)d_in[1];
    const float* w_hh = (const float*)d_in[2];
    const float* bias = (const float*)d_in[3];
    const float* fc_w = (const float*)d_in[4];
    const float* fc_b = (const float*)d_in[5];

    float* out = (float*)d_out;
    float* h_n = out + BATCH;
    float* c_n = h_n + (size_t)BATCH*SEQ*HID;

    unsigned* h_ex = (unsigned*)d_ws;                            // 2*256*256*4 = 512 KB
    int* flags = (int*)((char*)d_ws + (size_t)2*BATCH*HID*4);    // 2 KB; 0xAA poison < 0

    lstm_kernel<<<NBLK, 256, 0, stream>>>(x, w_ih, w_hh, bias, fc_w, fc_b,
                                          out, h_n, c_n, h_ex, flags);
}

// Round 5
// 7179.962 us; speedup vs baseline: 3.1321x; 3.1321x over previous
//
#include <hip/hip_runtime.h>
#include <stdint.h>

#define BATCH 256
#define SEQ   365
#define HID   256
#define INSZ  32
#define NGATE 1024
#define KTOT  288            // INSZ + HID
#define NKC   9              // K chunks of 32
#define AS    296            // shorts per A row (148 dw; with XOR swizzle -> 2-way banks, free)
#define WTOT  (KTOT*NGATE)   // 294912 elements per weight array

typedef __bf16 bf16x8 __attribute__((ext_vector_type(8)));
typedef short  s16x8  __attribute__((ext_vector_type(8)));
typedef float  f32x4  __attribute__((ext_vector_type(4)));

__device__ __forceinline__ unsigned short f2bf(float f) {
    unsigned u = __float_as_uint(f);
    u += 0x7FFFu + ((u >> 16) & 1u);          // round-to-nearest-even
    return (unsigned short)(u >> 16);
}
__device__ __forceinline__ float bf2f(unsigned short h) {
    return __uint_as_float(((unsigned)h) << 16);
}
__device__ __forceinline__ float sigm(float x) { return 1.f / (1.f + __expf(-x)); }
__device__ __forceinline__ float tanh_f(float x) {
    float e = __expf(-2.f * fabsf(x));
    float r = (1.f - e) / (1.f + e);
    return copysignf(r, x);
}

// One-time: W^T (w_ih stacked over w_hh) -> bf16 hi/lo in MFMA-B-fragment order.
// B frag (16x16x32): lane l holds col n = tile*16 + (l&15), k = c*32 + (l>>4)*8 + j.
// Storage: wsw[((tile*NKC + c)*64 + l)*8 + j]  (hi), +WTOT (lo).
__global__ void swizzle_w(const float* __restrict__ w_ih,
                          const float* __restrict__ w_hh,
                          unsigned short* __restrict__ wsw)
{
    int idx = blockIdx.x*256 + threadIdx.x;      // idx = k*1024 + n  (coalesced reads)
    int k = idx >> 10, n = idx & 1023;
    float v = (k < INSZ) ? w_ih[k*NGATE + n] : w_hh[(k-INSZ)*NGATE + n];
    unsigned short hi = f2bf(v);
    unsigned short lo = f2bf(v - bf2f(hi));
    int t = n >> 4, l15 = n & 15, c = k >> 5, q = (k >> 3) & 3, j = k & 7;
    int off = ((t*NKC + c)*64 + q*16 + l15)*8 + j;
    wsw[off]        = hi;
    wsw[WTOT + off] = lo;
}

// Physical LDS address for A element (row r, logical k): 16B blocks XOR-swizzled by r&3.
__device__ __forceinline__ int a_addr(int r, int k) {
    return r*AS + ((((k >> 3) ^ (r & 3))) << 3) + (k & 7);
}

__global__ __launch_bounds__(512, 2) void lstm_seq(
    const float* __restrict__ x,      // [B][SEQ][INSZ]
    const unsigned short* __restrict__ wsw,
    const float* __restrict__ bias,   // [NGATE]
    const float* __restrict__ fc_w,   // [HID]
    const float* __restrict__ fc_b,   // [1]
    float* __restrict__ out,          // [B]
    float* __restrict__ h_n,          // [B][SEQ][HID]
    float* __restrict__ c_n)          // [B][SEQ][HID]
{
    __shared__ short a_hi[16*AS];     // A = [x_t | h] hi, XOR-swizzled blocks
    __shared__ short a_lo[16*AS];
    __shared__ float red[16*17];      // FC reduction

    const int tid  = threadIdx.x;
    const int b0   = blockIdx.x * 16;       // this block owns batch rows b0..b0+15
    const int wv   = tid >> 6, lane = tid & 63;
    const int l15  = lane & 15, q = lane >> 4;

    // wave wv owns hidden cols [wv*32, wv*32+32): gate G tile pair {G*16+2wv, G*16+2wv+1}
    float bia[4][2];
    #pragma unroll
    for (int G = 0; G < 4; ++G)
        #pragma unroll
        for (int u = 0; u < 2; ++u)
            bia[G][u] = bias[G*HID + wv*32 + u*16 + l15];

    float cst[2][4];                  // c state: [tile u][row i], row = q*4+i, col = wv*32+u*16+l15
    #pragma unroll
    for (int u = 0; u < 2; ++u)
        #pragma unroll
        for (int i = 0; i < 4; ++i) cst[u][i] = 0.f;

    // ---- initial staging: zero all of A, then x(s=0) ----
    for (int i = tid; i < 16*AS; i += 512) { a_hi[i] = 0; a_lo[i] = 0; }
    __syncthreads();   // zeros visible before x-overwrite (different threads touch same rows)
    {
        int r = tid >> 5, k = tid & 31;
        float v = x[((size_t)(b0 + r)*SEQ + 0)*INSZ + k];
        unsigned short hi = f2bf(v);
        int pa = a_addr(r, k);
        a_hi[pa] = (short)hi;
        a_lo[pa] = (short)f2bf(v - bf2f(hi));
    }

    for (int s = 0; s < SEQ; ++s) {
        __syncthreads();              // A ready

        // ---- MFMA phase: A[16x288] (LDS) x W-frags streamed from L2 ----
        f32x4 acc[4][2];
        #pragma unroll
        for (int G = 0; G < 4; ++G)
            #pragma unroll
            for (int u = 0; u < 2; ++u) acc[G][u] = (f32x4){0.f,0.f,0.f,0.f};

        const int qs = (q ^ (l15 & 3)) << 3;   // swizzled 16B block within chunk
        #pragma unroll 3
        for (int c = 0; c < NKC; ++c) {
            int pk = l15*AS + c*32 + qs;
            bf16x8 ah = __builtin_bit_cast(bf16x8, *(const s16x8*)&a_hi[pk]);
            bf16x8 al = __builtin_bit_cast(bf16x8, *(const s16x8*)&a_lo[pk]);
            #pragma unroll
            for (int G = 0; G < 4; ++G)
                #pragma unroll
                for (int u = 0; u < 2; ++u) {
                    int tile = G*16 + wv*2 + u;
                    const unsigned short* wp = wsw + ((size_t)(tile*NKC + c)*64 + lane)*8;
                    bf16x8 bh = __builtin_bit_cast(bf16x8, *(const s16x8*)wp);
                    bf16x8 bl = __builtin_bit_cast(bf16x8, *(const s16x8*)(wp + WTOT));
                    acc[G][u] = __builtin_amdgcn_mfma_f32_16x16x32_bf16(ah, bh, acc[G][u], 0,0,0);
                    acc[G][u] = __builtin_amdgcn_mfma_f32_16x16x32_bf16(ah, bl, acc[G][u], 0,0,0);
                    acc[G][u] = __builtin_amdgcn_mfma_f32_16x16x32_bf16(al, bh, acc[G][u], 0,0,0);
                }
        }

        // ---- epilogue (pure register): D layout col=lane&15, row=(lane>>4)*4+i ----
        float hnv[2][4];
        #pragma unroll
        for (int u = 0; u < 2; ++u)
            #pragma unroll
            for (int i = 0; i < 4; ++i) {
                float f  = acc[0][u][i] + bia[0][u];
                float ii = acc[1][u][i] + bia[1][u];
                float o  = acc[2][u][i] + bia[2][u];
                float gg = acc[3][u][i] + bia[3][u];
                float cn = sigm(f)*cst[u][i] + sigm(ii)*tanh_f(gg);
                float hn = sigm(o)*tanh_f(cn);
                cst[u][i] = cn;
                hnv[u][i] = hn;
                size_t oi = ((size_t)(b0 + q*4 + i)*SEQ + s)*HID + wv*32 + u*16 + l15;
                h_n[oi] = hn;
                c_n[oi] = cn;
            }

        __syncthreads();              // all waves done reading A

        // ---- write h(s) into A's h-region (hi/lo), stage x(s+1) ----
        #pragma unroll
        for (int u = 0; u < 2; ++u)
            #pragma unroll
            for (int i = 0; i < 4; ++i) {
                int r = q*4 + i;
                int k = INSZ + wv*32 + u*16 + l15;
                unsigned short hi = f2bf(hnv[u][i]);
                int pa = a_addr(r, k);
                a_hi[pa] = (short)hi;
                a_lo[pa] = (short)f2bf(hnv[u][i] - bf2f(hi));
            }
        if (s + 1 < SEQ) {
            int r = tid >> 5, k = tid & 31;
            float v = x[((size_t)(b0 + r)*SEQ + (s+1))*INSZ + k];
            unsigned short hi = f2bf(v);
            int pa = a_addr(r, k);
            a_hi[pa] = (short)hi;
            a_lo[pa] = (short)f2bf(v - bf2f(hi));
        }
    }

    // ---- final FC: out[b] = h(SEQ-1) . fc_w + fc_b (hi+lo reconstruct) ----
    __syncthreads();
    if (tid < 256) {
        int r = tid >> 4, seg = tid & 15;
        float acc = 0.f;
        #pragma unroll
        for (int d = 0; d < 16; ++d) {
            int j = seg*16 + d;
            int pa = a_addr(r, INSZ + j);
            acc += (bf2f((unsigned short)a_hi[pa]) + bf2f((unsigned short)a_lo[pa])) * fc_w[j];
        }
        red[r*17 + seg] = acc;
    }
    __syncthreads();
    if (tid < 16) {
        float acc = fc_b[0];
        #pragma unroll
        for (int p = 0; p < 16; ++p) acc += red[tid*17 + p];
        out[b0 + tid] = acc;
    }
}

extern "C" void kernel_launch(void* const* d_in, const int* in_sizes, int n_in,
                              void* d_out, int out_size, void* d_ws, size_t ws_size,
                              hipStream_t stream) {
    const float* x    = (const float*)d_in[0];
    const float* w_ih = (const float*)d_in[1];
    const float* w_hh = (const float*)d_in[2];
    const float* bias = (const float*)d_in[3];
    const float* fc_w = (const float*)d_in[4];
    const float* fc_b = (const float*)d_in[5];

    float* out = (float*)d_out;
    float* h_n = out + BATCH;
    float* c_n = h_n + (size_t)BATCH*SEQ*HID;

    unsigned short* wsw = (unsigned short*)d_ws;   // 2 x 576 KB = 1.125 MB

    swizzle_w<<<(2*WTOT/2)/256/2*2 == 0 ? 1152 : 1152, 256, 0, stream>>>(w_ih, w_hh, wsw);
    lstm_seq<<<16, 512, 0, stream>>>(x, wsw, bias, fc_w, fc_b, out, h_n, c_n);
}